// Round 1
// baseline (703.654 us; speedup 1.0000x reference)
//
#include <hip/hip_runtime.h>
#include <stdint.h>

#define AS1 __attribute__((address_space(1)))
#define AS3 __attribute__((address_space(3)))

typedef _Float16 f16x8 __attribute__((ext_vector_type(8)));
typedef float f32x4 __attribute__((ext_vector_type(4)));

__device__ __forceinline__ unsigned short f32_f16(float f) {
  union { _Float16 h; unsigned short u; } v; v.h = (_Float16)f; return v.u;
}
__device__ __forceinline__ float f16_f32(unsigned short u) {
  union { _Float16 h; unsigned short u; } v; v.u = u; return (float)v.h;
}
// plain staging (L1+L2 cached) — for the GEMM
__device__ __forceinline__ void gl_lds16(const unsigned short* g, unsigned short* l) {
  __builtin_amdgcn_global_load_lds((const AS1 unsigned int*)g, (AS3 unsigned int*)l, 16, 0, 0);
}
// coherent staging — bypass L1+L2, read the Infinity Cache (R6/R9-proven)
__device__ __forceinline__ void gl_lds16_coh(const unsigned short* g, unsigned short* l) {
  __builtin_amdgcn_global_load_lds((const AS1 unsigned int*)g, (AS3 unsigned int*)l, 16, 0, 17);
}
// L2 staging — bypass L1 only (fast path: reads own-XCD L2)
__device__ __forceinline__ void gl_lds16_l2(const unsigned short* g, unsigned short* l) {
  __builtin_amdgcn_global_load_lds((const AS1 unsigned int*)g, (AS3 unsigned int*)l, 16, 0, 1);
}
// sc0 scalar load: bypass L1, read own-XCD L2 (R10-proven instruction)
__device__ __forceinline__ unsigned ld_sc0(const unsigned* p) {
  unsigned v;
  asm volatile("global_load_dword %0, %1, off sc0\n\ts_waitcnt vmcnt(0)"
               : "=v"(v) : "v"(p) : "memory");
  return v;
}
// sc0 store: write through L1 to own-XCD L2, leave line valid there (proven)
__device__ __forceinline__ void st_sc0(unsigned* p, unsigned v) {
  asm volatile("global_store_dword %0, %1, off sc0" :: "v"(p), "v"(v) : "memory");
}

// ---------------- fused f32 -> fp16 conversion (facts, Wr, W, mem_old) ----------
__global__ void cvt_all(const float4* __restrict__ sf, ushort4* __restrict__ df,
                        const float4* __restrict__ s1, ushort4* __restrict__ d1,
                        const float4* __restrict__ s2, ushort4* __restrict__ d2,
                        const float4* __restrict__ sm, ushort4* __restrict__ dm) {
  int i = blockIdx.x * blockDim.x + threadIdx.x;
  int st = gridDim.x * blockDim.x;
  for (int k = i; k < 4751360; k += st) {
    const float4* s; ushort4* d; int off;
    if (k < 4194304)      { s = sf; d = df; off = k; }
    else if (k < 4456448) { s = s1; d = d1; off = k - 4194304; }
    else if (k < 4718592) { s = s2; d = d2; off = k - 4456448; }
    else                  { s = sm; d = dm; off = k - 4718592; }
    float4 v = s[off];
    ushort4 o;
    o.x = f32_f16(v.x); o.y = f32_f16(v.y); o.z = f32_f16(v.z); o.w = f32_f16(v.w);
    d[off] = o;
  }
}

// ---------------- phase 1: C[t][b][0:2048] = facts(b,t,:) @ [Wr|W]^T (fp16 out) ----
// BK=64 (16 K-tiles), XOR source-swizzle staging, scalar C-store (proven R9/R11).
__global__ __launch_bounds__(256, 2) void gemm_fw(
    const unsigned short* __restrict__ A,
    const unsigned short* __restrict__ Bt,
    unsigned short* __restrict__ Ct)
{
  __shared__ __align__(16) unsigned short As[128 * 64];
  __shared__ __align__(16) unsigned short Bs[128 * 64];
  const int tid = threadIdx.x;
  const int lane = tid & 63;
  const int wv = tid >> 6;
  const int q = lane >> 4, ln = lane & 15;
  const int bm = blockIdx.x, bn = blockIdx.y;
  const int wm = (wv >> 1) * 64, wn = (wv & 1) * 64;

  f32x4 acc[4][4] = {};

  for (int kt = 0; kt < 1024; kt += 64) {
    __syncthreads();
#pragma unroll
    for (int rr = 0; rr < 4; ++rr) {
      int chunk = rr * 256 + tid;          // 0..1023
      int r = chunk >> 3, c = chunk & 7;   // 8 chunks (16B) per 128B row
      int cs = c ^ (r & 7);                // source chunk for this LDS pos
      gl_lds16(A + (size_t)(bm * 128 + r) * 1024 + kt + cs * 8, As + chunk * 8);
      gl_lds16(Bt + (size_t)(bn * 128 + r) * 1024 + kt + cs * 8, Bs + chunk * 8);
    }
    __syncthreads();
    f16x8 af[4][2], bfr[4][2];
#pragma unroll
    for (int mi = 0; mi < 4; ++mi)
#pragma unroll
      for (int kk = 0; kk < 2; ++kk)
        af[mi][kk] = *(const f16x8*)(As + (wm + mi * 16 + ln) * 64 + (((q + 4 * kk) ^ (ln & 7)) * 8));
#pragma unroll
    for (int ni = 0; ni < 4; ++ni)
#pragma unroll
      for (int kk = 0; kk < 2; ++kk)
        bfr[ni][kk] = *(const f16x8*)(Bs + (wn + ni * 16 + ln) * 64 + (((q + 4 * kk) ^ (ln & 7)) * 8));
#pragma unroll
    for (int kk = 0; kk < 2; ++kk)
#pragma unroll
      for (int mi = 0; mi < 4; ++mi)
#pragma unroll
        for (int ni = 0; ni < 4; ++ni)
          acc[mi][ni] = __builtin_amdgcn_mfma_f32_16x16x32_f16(af[mi][kk], bfr[ni][kk], acc[mi][ni], 0, 0, 0);
  }
#pragma unroll
  for (int mi = 0; mi < 4; ++mi)
#pragma unroll
    for (int ni = 0; ni < 4; ++ni)
#pragma unroll
      for (int r2 = 0; r2 < 4; ++r2) {
        int trow = wm + mi * 16 + q * 4 + r2;   // == t
        int col = bn * 128 + wn + ni * 16 + ln; // 0..2047: [fWr | fW]
        Ct[(size_t)trow * 262144 + (size_t)bm * 2048 + col] = f32_f16(acc[mi][ni][r2]);
      }
}

// ---------------- phase 2: the recurrence (merged-matrix waves, 16 blocks/group) ----
// Grid 128 = 8 groups x 16 dim-slices; ga = blockIdx&7. Each wave holds BOTH
// Ur and U weight rows for its 16 dims (256 VGPRs) -> no xchg, 2 barriers/step,
// 4 independent MFMA accumulation chains, fwx(t+1) prefetched under the poll.
// Coherence identical to proven R9/R10 design: fast path = sc0 store/load on
// own-XCD L2 (runtime XCD-uniformity verified), fallback = IC atomics.
__global__ __launch_bounds__(256, 1) void gru_recur(
    const unsigned short* __restrict__ fwx,   // [128 t][128 b][2048] f16
    const float* __restrict__ Urw, const float* __restrict__ Urb,
    const float* __restrict__ Uw,  const float* __restrict__ Ub,
    const float* __restrict__ g,              // [128 b][128 t]
    const float* __restrict__ mem_old,        // [128][1024]
    const int* __restrict__ nfp,              // [128]
    unsigned short* __restrict__ hbf,         // [2][128][1024] f16
    unsigned int* __restrict__ flg,           // [8 ga][16 blk][32 pad] u32
    unsigned int* __restrict__ xcc,           // [8 ga][16 blk][32 pad] u32
    float* __restrict__ out)                  // [128][1024] f32
{
  __shared__ __align__(16) unsigned char At[32768]; // 16 rows x 2048B, dense
  __shared__ int fast_lds;

  const int tid = threadIdx.x;
  const int lane = tid & 63;
  const int w = tid >> 6;           // 0..3 : dim sub-tile within the block
  const int q = lane >> 4;
  const int ln = lane & 15;
  const int ga = blockIdx.x & 7;    // XCD-local group under round-robin dispatch
  const int dsl = blockIdx.x >> 3;  // dim-slice within group, 0..15
  const int b0 = ga * 16;
  const int n_g = dsl * 64 + w * 16 + ln;

  // --- XCD-uniformity handshake (R10-proven, over the always-correct IC path) ---
  unsigned my_xcc;
  asm("s_getreg_b32 %0, hwreg(HW_REG_XCC_ID)" : "=s"(my_xcc));
  if (tid == 0)
    __hip_atomic_store(&xcc[(ga * 16 + dsl) * 32], my_xcc + 1u,
                       __ATOMIC_RELAXED, __HIP_MEMORY_SCOPE_AGENT);
  if (w == 0) {
    unsigned* xp = &xcc[(ga * 16 + (lane & 15)) * 32];
    unsigned v;
    for (;;) {
      v = __hip_atomic_load(xp, __ATOMIC_RELAXED, __HIP_MEMORY_SCOPE_AGENT);
      if (__ballot(lane < 16 && v == 0u) == 0ull) break;
    }
    unsigned long long bad = __ballot(lane < 16 && v != my_xcc + 1u);
    if (lane == 0) fast_lds = (bad == 0ull);
  }

  // --- one-time: BOTH weight matrices into registers (B-fragment: n=ln, k=q*8+j) ---
  f16x8 bwr[32], bwu[32];
#pragma unroll
  for (int ks = 0; ks < 32; ++ks) {
    {
      const float* s = Urw + (size_t)n_g * 1024 + ks * 32 + q * 8;
      float4 x0 = *(const float4*)s;
      float4 x1 = *(const float4*)(s + 4);
      f16x8 t;
      t[0] = (_Float16)x0.x; t[1] = (_Float16)x0.y;
      t[2] = (_Float16)x0.z; t[3] = (_Float16)x0.w;
      t[4] = (_Float16)x1.x; t[5] = (_Float16)x1.y;
      t[6] = (_Float16)x1.z; t[7] = (_Float16)x1.w;
      bwr[ks] = t;
    }
    {
      const float* s = Uw + (size_t)n_g * 1024 + ks * 32 + q * 8;
      float4 x0 = *(const float4*)s;
      float4 x1 = *(const float4*)(s + 4);
      f16x8 t;
      t[0] = (_Float16)x0.x; t[1] = (_Float16)x0.y;
      t[2] = (_Float16)x0.z; t[3] = (_Float16)x0.w;
      t[4] = (_Float16)x1.x; t[5] = (_Float16)x1.y;
      t[6] = (_Float16)x1.z; t[7] = (_Float16)x1.w;
      bwu[ks] = t;
    }
  }
  const float biasr = Urb[n_g];
  const float biasu = Ub[n_g];

  const f32x4 zero4 = {0.f, 0.f, 0.f, 0.f};
  f32x4 ar[2] = {zero4, zero4};
  f32x4 au[2] = {zero4, zero4};

  float h_own[4];
  int nf[4];
#pragma unroll
  for (int r = 0; r < 4; ++r) {
    int b = b0 + q * 4 + r;
    h_own[r] = mem_old[(size_t)b * 1024 + n_g];
    nf[r] = nfp[b];
  }

  __syncthreads();
  const int fast = fast_lds;

  // A-fragment read bases: row ln, chunk(ks) = (q + 4*ks) ^ (ln&7).
  const int swz = ln & 7;
  const int rowb = ln * 2048 + (q ^ (swz & 3)) * 16;
  const int be = rowb + ((swz >> 2) << 6);        // ks even
  const int bo = rowb + (((swz >> 2) ^ 1) << 6);  // ks odd

  // epilogue operands for t=0 (prefetched; steady state refills under the poll)
  float fwrv[4], fwv[4], gv[4];
#pragma unroll
  for (int r = 0; r < 4; ++r) {
    int b = b0 + q * 4 + r;
    size_t base = (size_t)b * 2048;
    fwrv[r] = f16_f32(fwx[base + n_g]);
    fwv[r]  = f16_f32(fwx[base + 1024 + n_g]);
    gv[r]   = g[b * 128 + 0];
  }

  for (int t = 0; t < 128; ++t) {
    // stage h(t) group tile (16 x 1024 f16 = 32KB): 8 x 1KB chunks per wave
    const unsigned short* hsrc = hbf + (size_t)(t & 1) * 131072 + (size_t)b0 * 1024;
    if (fast) {
#pragma unroll
      for (int j = 0; j < 8; ++j) {
        int blk = w * 8 + j;
        int m = blk >> 1, kh = blk & 1;
        gl_lds16_l2(hsrc + m * 1024 + kh * 512 + ((lane ^ (m & 7)) * 8),
                    (unsigned short*)(At + m * 2048 + kh * 1024));
      }
    } else {
#pragma unroll
      for (int j = 0; j < 8; ++j) {
        int blk = w * 8 + j;
        int m = blk >> 1, kh = blk & 1;
        gl_lds16_coh(hsrc + m * 1024 + kh * 512 + ((lane ^ (m & 7)) * 8),
                     (unsigned short*)(At + m * 2048 + kh * 1024));
      }
    }
    __syncthreads(); // drains vmcnt -> staging complete

    // MFMA k-loop: one A read feeds both matrices; even/odd ks split the chains
#pragma unroll
    for (int ks = 0; ks < 32; ++ks) {
      const unsigned char* ap = At + (((ks & 1) ? bo : be) + ((ks >> 1) << 7));
      f16x8 a = *(const f16x8*)ap;
      ar[ks & 1] = __builtin_amdgcn_mfma_f32_16x16x32_f16(a, bwr[ks], ar[ks & 1], 0, 0, 0);
      au[ks & 1] = __builtin_amdgcn_mfma_f32_16x16x32_f16(a, bwu[ks], au[ks & 1], 0, 0, 0);
    }

    // epilogue: every wave combines r-side and u-side for its own 16 dims
    unsigned int* hb32 = (unsigned int*)(hbf + (size_t)((t + 1) & 1) * 131072);
#pragma unroll
    for (int r = 0; r < 4; ++r) {
      float rv = ar[0][r] + ar[1][r] + biasr + fwrv[r];
      float uv = au[0][r] + au[1][r] + biasu;
      float rg = 1.0f / (1.0f + __expf(-rv));
      float pre = fwv[r] + rg * uv;
      float e2 = __expf(-2.0f * fabsf(pre));
      float th = (1.0f - e2) / (1.0f + e2);
      float ht = copysignf(th, pre);
      float hn = gv[r] * ht + (1.0f - gv[r]) * h_own[r];
      h_own[r] = hn;
      int b = b0 + q * 4 + r;
      // pack adjacent dims (n_g even|odd) into u32
      unsigned short hu = f32_f16(hn);
      unsigned short pu = (unsigned short)__shfl_xor((int)hu, 1, 64);
      if (!(ln & 1)) {
        unsigned val = (unsigned)hu | ((unsigned)pu << 16);
        unsigned* dst = &hb32[(b * 1024 + n_g) >> 1];
        if (fast) st_sc0(dst, val);                          // write-through to own-XCD L2
        else __hip_atomic_store(dst, val, __ATOMIC_RELAXED,  // write-through to IC
                                __HIP_MEMORY_SCOPE_AGENT);
      }
      if (t == nf[r] - 1) out[(size_t)b * 1024 + n_g] = hn;
    }
    ar[0] = zero4; ar[1] = zero4; au[0] = zero4; au[1] = zero4;

    __syncthreads(); // all waves' h stores drained (compiler vmcnt(0) + barrier);
                     // also orders this step's At reads before next staging
    if (t < 127) {
      unsigned* myf = &flg[(ga * 16 + dsl) * 32];
      if (tid == 0) {
        if (fast) {
          asm volatile("s_waitcnt vmcnt(0)" ::: "memory"); // belt & braces
          st_sc0(myf, (unsigned)(t + 1));
        } else {
          __hip_atomic_store(myf, (unsigned)(t + 1),
                             __ATOMIC_RELAXED, __HIP_MEMORY_SCOPE_AGENT);
        }
      }
      // prefetch next-step epilogue operands; IC latency hides under the poll
#pragma unroll
      for (int r = 0; r < 4; ++r) {
        int b = b0 + q * 4 + r;
        size_t base = (size_t)(t + 1) * 262144 + (size_t)b * 2048;
        fwrv[r] = f16_f32(fwx[base + n_g]);
        fwv[r]  = f16_f32(fwx[base + 1024 + n_g]);
        gv[r]   = g[b * 128 + (t + 1)];
      }
      // every wave polls all 16 group flags itself -> no release barrier needed
      unsigned int* fp = &flg[(ga * 16 + (lane & 15)) * 32];
      if (fast) {
        for (int it = 0;; ++it) {
          unsigned v = ((it & 7) == 7)
              ? __hip_atomic_load(fp, __ATOMIC_RELAXED, __HIP_MEMORY_SCOPE_AGENT)
              : ld_sc0(fp);
          if (__ballot(lane < 16 && v < (unsigned)(t + 1)) == 0ull) break;
        }
      } else {
        for (;;) {
          unsigned v = __hip_atomic_load(fp, __ATOMIC_RELAXED, __HIP_MEMORY_SCOPE_AGENT);
          if (__ballot(lane < 16 && v < (unsigned)(t + 1)) == 0ull) break;
        }
      }
    }
  }
}

extern "C" void kernel_launch(void* const* d_in, const int* in_sizes, int n_in,
                              void* d_out, int out_size, void* d_ws, size_t ws_size,
                              hipStream_t stream) {
  const float* facts     = (const float*)d_in[0]; // [128][128][1024]
  const int*   num_facts = (const int*)d_in[1];   // [128]
  const float* g         = (const float*)d_in[2]; // [128][128][1]
  const float* mem_old   = (const float*)d_in[3]; // [128][1][1024]
  const float* Wr        = (const float*)d_in[4]; // [1024][1024]
  const float* Urw       = (const float*)d_in[5];
  const float* Urb       = (const float*)d_in[6];
  const float* W         = (const float*)d_in[7];
  const float* Uw        = (const float*)d_in[8];
  const float* Ub        = (const float*)d_in[9];

  // workspace layout (f16 elements unless noted)
  unsigned short* facts_h = (unsigned short*)d_ws;        // 16,777,216
  unsigned short* wstack  = facts_h + 16777216;           //  2,097,152 ([Wr|W])
  unsigned short* fwx     = wstack + 2097152;             // 33,554,432 ([t][b][2048])
  unsigned short* hbf     = fwx + 33554432;               //    262,144 (2 x [128][1024])
  unsigned int*   flg     = (unsigned int*)(hbf + 262144);// 8*32*32 u32 = 32KB (16 used/group)
  unsigned int*   xcc     = flg + 8192;                   // 8*32*32 u32 = 32KB
  float* out = (float*)d_out;

  hipMemsetAsync(flg, 0, 2 * 8 * 32 * 32 * 4, stream);    // flg + xcc
  cvt_all<<<4096, 256, 0, stream>>>(
      (const float4*)facts,   (ushort4*)facts_h,
      (const float4*)Wr,      (ushort4*)wstack,
      (const float4*)W,       (ushort4*)(wstack + 1048576),
      (const float4*)mem_old, (ushort4*)hbf);
  gemm_fw<<<dim3(128, 16), 256, 0, stream>>>(facts_h, wstack, fwx);
  gru_recur<<<128, 256, 0, stream>>>(fwx, Urw, Urb, Uw, Ub, g, mem_old, num_facts, hbf, flg, xcc, out);
}

// Round 3
// 663.293 us; speedup vs baseline: 1.0609x; 1.0609x over previous
//
#include <hip/hip_runtime.h>
#include <stdint.h>

#define AS1 __attribute__((address_space(1)))
#define AS3 __attribute__((address_space(3)))

typedef _Float16 f16x8 __attribute__((ext_vector_type(8)));
typedef float f32x4 __attribute__((ext_vector_type(4)));

__device__ __forceinline__ unsigned short f32_f16(float f) {
  union { _Float16 h; unsigned short u; } v; v.h = (_Float16)f; return v.u;
}
__device__ __forceinline__ float f16_f32(unsigned short u) {
  union { _Float16 h; unsigned short u; } v; v.u = u; return (float)v.h;
}
// plain staging (L1+L2 cached) — for the GEMM
__device__ __forceinline__ void gl_lds16(const unsigned short* g, unsigned short* l) {
  __builtin_amdgcn_global_load_lds((const AS1 unsigned int*)g, (AS3 unsigned int*)l, 16, 0, 0);
}
// coherent staging — bypass L1+L2, read the Infinity Cache (R6/R9-proven)
__device__ __forceinline__ void gl_lds16_coh(const unsigned short* g, unsigned short* l) {
  __builtin_amdgcn_global_load_lds((const AS1 unsigned int*)g, (AS3 unsigned int*)l, 16, 0, 17);
}
// L2 staging — bypass L1 only (fast path: reads own-XCD L2)
__device__ __forceinline__ void gl_lds16_l2(const unsigned short* g, unsigned short* l) {
  __builtin_amdgcn_global_load_lds((const AS1 unsigned int*)g, (AS3 unsigned int*)l, 16, 0, 1);
}
// sc0 scalar load: bypass L1, read own-XCD L2 (R10-proven instruction)
__device__ __forceinline__ unsigned ld_sc0(const unsigned* p) {
  unsigned v;
  asm volatile("global_load_dword %0, %1, off sc0\n\ts_waitcnt vmcnt(0)"
               : "=v"(v) : "v"(p) : "memory");
  return v;
}
// sc0 store: write through L1 to own-XCD L2, leave line valid there (proven)
__device__ __forceinline__ void st_sc0(unsigned* p, unsigned v) {
  asm volatile("global_store_dword %0, %1, off sc0" :: "v"(p), "v"(v) : "memory");
}

// ---------------- fused f32 -> fp16 conversion (facts, Wr, W, mem_old) ----------
__global__ void cvt_all(const float4* __restrict__ sf, ushort4* __restrict__ df,
                        const float4* __restrict__ s1, ushort4* __restrict__ d1,
                        const float4* __restrict__ s2, ushort4* __restrict__ d2,
                        const float4* __restrict__ sm, ushort4* __restrict__ dm) {
  int i = blockIdx.x * blockDim.x + threadIdx.x;
  int st = gridDim.x * blockDim.x;
  for (int k = i; k < 4751360; k += st) {
    const float4* s; ushort4* d; int off;
    if (k < 4194304)      { s = sf; d = df; off = k; }
    else if (k < 4456448) { s = s1; d = d1; off = k - 4194304; }
    else if (k < 4718592) { s = s2; d = d2; off = k - 4456448; }
    else                  { s = sm; d = dm; off = k - 4718592; }
    float4 v = s[off];
    ushort4 o;
    o.x = f32_f16(v.x); o.y = f32_f16(v.y); o.z = f32_f16(v.z); o.w = f32_f16(v.w);
    d[off] = o;
  }
}

// ---------------- phase 1: C[t][b][0:2048] = facts(b,t,:) @ [Wr|W]^T (fp16 out) ----
// BK=64 (16 K-tiles), XOR source-swizzle staging, scalar C-store (proven R9/R11).
__global__ __launch_bounds__(256, 2) void gemm_fw(
    const unsigned short* __restrict__ A,
    const unsigned short* __restrict__ Bt,
    unsigned short* __restrict__ Ct)
{
  __shared__ __align__(16) unsigned short As[128 * 64];
  __shared__ __align__(16) unsigned short Bs[128 * 64];
  const int tid = threadIdx.x;
  const int lane = tid & 63;
  const int wv = tid >> 6;
  const int q = lane >> 4, ln = lane & 15;
  const int bm = blockIdx.x, bn = blockIdx.y;
  const int wm = (wv >> 1) * 64, wn = (wv & 1) * 64;

  f32x4 acc[4][4] = {};

  for (int kt = 0; kt < 1024; kt += 64) {
    __syncthreads();
#pragma unroll
    for (int rr = 0; rr < 4; ++rr) {
      int chunk = rr * 256 + tid;          // 0..1023
      int r = chunk >> 3, c = chunk & 7;   // 8 chunks (16B) per 128B row
      int cs = c ^ (r & 7);                // source chunk for this LDS pos
      gl_lds16(A + (size_t)(bm * 128 + r) * 1024 + kt + cs * 8, As + chunk * 8);
      gl_lds16(Bt + (size_t)(bn * 128 + r) * 1024 + kt + cs * 8, Bs + chunk * 8);
    }
    __syncthreads();
    f16x8 af[4][2], bfr[4][2];
#pragma unroll
    for (int mi = 0; mi < 4; ++mi)
#pragma unroll
      for (int kk = 0; kk < 2; ++kk)
        af[mi][kk] = *(const f16x8*)(As + (wm + mi * 16 + ln) * 64 + (((q + 4 * kk) ^ (ln & 7)) * 8));
#pragma unroll
    for (int ni = 0; ni < 4; ++ni)
#pragma unroll
      for (int kk = 0; kk < 2; ++kk)
        bfr[ni][kk] = *(const f16x8*)(Bs + (wn + ni * 16 + ln) * 64 + (((q + 4 * kk) ^ (ln & 7)) * 8));
#pragma unroll
    for (int kk = 0; kk < 2; ++kk)
#pragma unroll
      for (int mi = 0; mi < 4; ++mi)
#pragma unroll
        for (int ni = 0; ni < 4; ++ni)
          acc[mi][ni] = __builtin_amdgcn_mfma_f32_16x16x32_f16(af[mi][kk], bfr[ni][kk], acc[mi][ni], 0, 0, 0);
  }
#pragma unroll
  for (int mi = 0; mi < 4; ++mi)
#pragma unroll
    for (int ni = 0; ni < 4; ++ni)
#pragma unroll
      for (int r2 = 0; r2 < 4; ++r2) {
        int trow = wm + mi * 16 + q * 4 + r2;   // == t
        int col = bn * 128 + wn + ni * 16 + ln; // 0..2047: [fWr | fW]
        Ct[(size_t)trow * 262144 + (size_t)bm * 2048 + col] = f32_f16(acc[mi][ni][r2]);
      }
}

// ---------------- phase 2: the recurrence (R9 topology + pipelined split-K staging) --
// Grid 256 = 8 groups x 32 dim-slices; ga = blockIdx&7; 4 waves, one matrix per
// wave-pair (32 MFMA/SIMD/step — R1 showed doubling this costs more than a barrier).
// New vs R9: (a) staging for h(t+1) issued at the BOTTOM of iter t, split into
// K-halves (lower dims from dsl 0..15, upper from dsl 16..31) with per-half flag
// polls; (b) loop top is a raw s_barrier (no full drain), upper half drained by a
// counted vmcnt AFTER the lower MFMA half; (c) fwx/g epilogue loads ride in flight
// through the counted wait; (d) acc chain split 2-way; (e) all waves poll -> no
// trailing release barrier. Coherence flavors (sc0 / IC-atomic fallback) unchanged.
__global__ __launch_bounds__(256, 1) void gru_recur(
    const unsigned short* __restrict__ fwx,   // [128 t][128 b][2048] f16
    const float* __restrict__ Urw, const float* __restrict__ Urb,
    const float* __restrict__ Uw,  const float* __restrict__ Ub,
    const float* __restrict__ g,              // [128 b][128 t]
    const float* __restrict__ mem_old,        // [128][1024]
    const int* __restrict__ nfp,              // [128]
    unsigned short* __restrict__ hbf,         // [2][128][1024] f16
    unsigned int* __restrict__ flg,           // [8 ga][32 blk][32 pad] u32
    unsigned int* __restrict__ xcc,           // [8 ga][32 blk][32 pad] u32
    float* __restrict__ out)                  // [128][1024] f32
{
  __shared__ __align__(16) unsigned char At[32768]; // 16 rows x 2048B, dense
  __shared__ float xchg[512];
  __shared__ int fast_lds;

  const int tid = threadIdx.x;
  const int lane = tid & 63;
  const int w = tid >> 6;
  const int q = lane >> 4;
  const int ln = lane & 15;
  const int matrix = w >> 1;
  const int ntile = w & 1;
  const int ga = blockIdx.x & 7;    // XCD-local group under round-robin dispatch
  const int dsl = blockIdx.x >> 3;  // dim-slice within group, 0..31
  const int b0 = ga * 16;
  const int n_g = dsl * 32 + ntile * 16 + ln;

  // --- XCD-uniformity handshake (R10-proven, over the always-correct IC path) ---
  unsigned my_xcc;
  asm("s_getreg_b32 %0, hwreg(HW_REG_XCC_ID)" : "=s"(my_xcc));
  if (tid == 0)
    __hip_atomic_store(&xcc[(ga * 32 + dsl) * 32], my_xcc + 1u,
                       __ATOMIC_RELAXED, __HIP_MEMORY_SCOPE_AGENT);
  if (w == 0) {
    unsigned* xp = &xcc[(ga * 32 + (lane & 31)) * 32];
    unsigned v;
    for (;;) {
      v = __hip_atomic_load(xp, __ATOMIC_RELAXED, __HIP_MEMORY_SCOPE_AGENT);
      if (__ballot(lane < 32 && v == 0u) == 0ull) break;
    }
    unsigned long long bad = __ballot(lane < 32 && v != my_xcc + 1u);
    if (lane == 0) fast_lds = (bad == 0ull);
  }

  // --- one-time: weights into registers (B-fragment layout: n=lane&15, k=q*8+j) ---
  const float* Wm = matrix ? Uw : Urw;
  f16x8 bw[32];
#pragma unroll
  for (int ks = 0; ks < 32; ++ks) {
    const float* s = Wm + (size_t)n_g * 1024 + ks * 32 + q * 8;
    float4 x0 = *(const float4*)s;
    float4 x1 = *(const float4*)(s + 4);
    f16x8 t;
    t[0] = (_Float16)x0.x; t[1] = (_Float16)x0.y;
    t[2] = (_Float16)x0.z; t[3] = (_Float16)x0.w;
    t[4] = (_Float16)x1.x; t[5] = (_Float16)x1.y;
    t[6] = (_Float16)x1.z; t[7] = (_Float16)x1.w;
    bw[ks] = t;
  }
  const float bias = (matrix ? Ub : Urb)[n_g];
  const f32x4 zero4 = {0.f, 0.f, 0.f, 0.f};
  f32x4 acc0 = {bias, bias, bias, bias};   // even-ks chain (carries the bias)
  f32x4 acc1 = zero4;                      // odd-ks chain

  float h_own[4] = {0.f, 0.f, 0.f, 0.f};
  int nf[4] = {0, 0, 0, 0};
  if (matrix == 0) {
#pragma unroll
    for (int r = 0; r < 4; ++r) {
      int b = b0 + q * 4 + r;
      h_own[r] = mem_old[(size_t)b * 1024 + n_g];
      nf[r] = nfp[b];
    }
  }

  __syncthreads();
  const int fast = fast_lds;

  // A-fragment read bases: row ln, chunk(ks) = (q + 4*ks) ^ (ln&7).
  const int swz = ln & 7;
  const int rowb = ln * 2048 + (q ^ (swz & 3)) * 16;
  const int be = rowb + ((swz >> 2) << 6);        // ks even
  const int bo = rowb + (((swz >> 2) ^ 1) << 6);  // ks odd

  // --- prologue: stage h(0) tile (mem_old, written by cvt_all), both halves ---
  {
    const unsigned short* hsrc = hbf + (size_t)b0 * 1024;
    if (fast) {
#pragma unroll
      for (int j = 0; j < 8; ++j) {
        int blk = w * 8 + j;
        int m = blk >> 1, kh = blk & 1;
        gl_lds16_l2(hsrc + m * 1024 + kh * 512 + ((lane ^ (m & 7)) * 8),
                    (unsigned short*)(At + m * 2048 + kh * 1024));
      }
    } else {
#pragma unroll
      for (int j = 0; j < 8; ++j) {
        int blk = w * 8 + j;
        int m = blk >> 1, kh = blk & 1;
        gl_lds16_coh(hsrc + m * 1024 + kh * 512 + ((lane ^ (m & 7)) * 8),
                     (unsigned short*)(At + m * 2048 + kh * 1024));
      }
    }
    asm volatile("s_waitcnt vmcnt(0)" ::: "memory"); // own staging drained
  }

  for (int t = 0; t < 128; ++t) {
    // ---- barrier #1: lower half of At(t) ready (each wave drained its own
    //      lower-stage writes before arriving here; see bottom-of-loop polls) ----
    __builtin_amdgcn_sched_barrier(0);
    __builtin_amdgcn_s_barrier();
    __builtin_amdgcn_sched_barrier(0);
    asm volatile("" ::: "memory");

    // epilogue operands for THIS t: exactly 12 loads (matrix0), stay in flight
    // through the counted vmcnt below, consumed after the MFMA loop.
    float fwrv[4], fwv[4], gv[4];
    if (matrix == 0) {
#pragma unroll
      for (int r = 0; r < 4; ++r) {
        int b = b0 + q * 4 + r;
        size_t base = (size_t)t * 262144 + (size_t)b * 2048;
        fwrv[r] = f16_f32(fwx[base + n_g]);
        fwv[r]  = f16_f32(fwx[base + 1024 + n_g]);
        gv[r]   = g[b * 128 + t];
      }
    }

    // MFMA lower half: ks 0..15 (dims 0..511), 2 independent chains
#pragma unroll
    for (int ks = 0; ks < 16; ++ks) {
      const unsigned char* ap = At + (((ks & 1) ? bo : be) + ((ks >> 1) << 7));
      f16x8 a = *(const f16x8*)ap;
      if (ks & 1) acc1 = __builtin_amdgcn_mfma_f32_16x16x32_f16(a, bw[ks], acc1, 0, 0, 0);
      else        acc0 = __builtin_amdgcn_mfma_f32_16x16x32_f16(a, bw[ks], acc0, 0, 0, 0);
    }

    // ---- barrier #2: upper half ready. Counted wait: the 4 upper-stage
    //      global_load_lds are the OLDEST outstanding vmem ops; matrix0 keeps
    //      its 12 epilogue loads (youngest) in flight. ----
    __builtin_amdgcn_sched_barrier(0);
    if (matrix == 0) asm volatile("s_waitcnt vmcnt(12)" ::: "memory");
    else             asm volatile("s_waitcnt vmcnt(0)" ::: "memory");
    __builtin_amdgcn_sched_barrier(0);
    __builtin_amdgcn_s_barrier();
    __builtin_amdgcn_sched_barrier(0);
    asm volatile("" ::: "memory");

    // MFMA upper half: ks 16..31 (dims 512..1023)
#pragma unroll
    for (int ks = 16; ks < 32; ++ks) {
      const unsigned char* ap = At + (((ks & 1) ? bo : be) + ((ks >> 1) << 7));
      f16x8 a = *(const f16x8*)ap;
      if (ks & 1) acc1 = __builtin_amdgcn_mfma_f32_16x16x32_f16(a, bw[ks], acc1, 0, 0, 0);
      else        acc0 = __builtin_amdgcn_mfma_f32_16x16x32_f16(a, bw[ks], acc0, 0, 0, 0);
    }

    if (matrix == 1) { // u = U h + U_b -> exchange to r-side waves
#pragma unroll
      for (int r = 0; r < 4; ++r)
        xchg[ntile * 256 + (q * 4 + r) * 16 + ln] = acc0[r] + acc1[r];
    }
    __syncthreads();
    if (matrix == 0) {
      unsigned int* hb32 = (unsigned int*)(hbf + (size_t)((t + 1) & 1) * 131072);
#pragma unroll
      for (int r = 0; r < 4; ++r) {
        float u = xchg[ntile * 256 + (q * 4 + r) * 16 + ln];
        float rv = acc0[r] + acc1[r] + fwrv[r];
        float rg = 1.0f / (1.0f + __expf(-rv));
        float pre = fwv[r] + rg * u;
        float e2 = __expf(-2.0f * fabsf(pre));
        float th = (1.0f - e2) / (1.0f + e2);
        float ht = copysignf(th, pre);
        float hn = gv[r] * ht + (1.0f - gv[r]) * h_own[r];
        h_own[r] = hn;
        int b = b0 + q * 4 + r;
        // pack adjacent dims (n_g even|odd) into u32
        unsigned short hu = f32_f16(hn);
        unsigned short pu = (unsigned short)__shfl_xor((int)hu, 1, 64);
        if (!(ln & 1)) {
          unsigned val = (unsigned)hu | ((unsigned)pu << 16);
          unsigned* dst = &hb32[(b * 1024 + n_g) >> 1];
          if (fast) st_sc0(dst, val);                          // write-through to own-XCD L2
          else __hip_atomic_store(dst, val, __ATOMIC_RELAXED,  // write-through to IC
                                  __HIP_MEMORY_SCOPE_AGENT);
        }
        if (t == nf[r] - 1) out[(size_t)b * 1024 + n_g] = hn;
      }
    }
    acc0[0] = bias; acc0[1] = bias; acc0[2] = bias; acc0[3] = bias;
    acc1 = zero4;

    __syncthreads(); // all waves' h stores drained (compiler vmcnt(0) + barrier);
                     // also: all waves finished reading At(t)

    if (t < 127) {
      if (tid == 0) {
        if (fast) {
          asm volatile("s_waitcnt vmcnt(0)" ::: "memory"); // belt & braces
          st_sc0(&flg[(ga * 32 + dsl) * 32], (unsigned)(t + 1));
        } else {
          __hip_atomic_store(&flg[(ga * 32 + dsl) * 32], (unsigned)(t + 1),
                             __ATOMIC_RELAXED, __HIP_MEMORY_SCOPE_AGENT);
        }
      }
      const unsigned short* hsrcN = hbf + (size_t)((t + 1) & 1) * 131072 + (size_t)b0 * 1024;
      unsigned int* fp = &flg[(ga * 32 + (lane & 31)) * 32];

      // poll LOWER producers (dsl 0..15 -> dims 0..511); all waves poll
      if (fast) {
        for (int it = 0;; ++it) {
          unsigned v = ((it & 7) == 7)
              ? __hip_atomic_load(fp, __ATOMIC_RELAXED, __HIP_MEMORY_SCOPE_AGENT)
              : ld_sc0(fp);
          if (__ballot(lane < 16 && v < (unsigned)(t + 1)) == 0ull) break;
        }
      } else {
        for (;;) {
          unsigned v = __hip_atomic_load(fp, __ATOMIC_RELAXED, __HIP_MEMORY_SCOPE_AGENT);
          if (__ballot(lane < 16 && v < (unsigned)(t + 1)) == 0ull) break;
        }
      }
      // stage lower half of h(t+1): rows m = w*4+j, bytes 0..1023 of each row
      if (fast) {
#pragma unroll
        for (int j = 0; j < 4; ++j) {
          int m = w * 4 + j;
          gl_lds16_l2(hsrcN + m * 1024 + ((lane ^ (m & 7)) * 8),
                      (unsigned short*)(At + m * 2048));
        }
      } else {
#pragma unroll
        for (int j = 0; j < 4; ++j) {
          int m = w * 4 + j;
          gl_lds16_coh(hsrcN + m * 1024 + ((lane ^ (m & 7)) * 8),
                       (unsigned short*)(At + m * 2048));
        }
      }
      // poll UPPER producers (dsl 16..31); first iteration's vmcnt(0) also
      // drains this wave's lower-stage writes (required before barrier #1)
      if (fast) {
        for (int it = 0;; ++it) {
          unsigned v = ((it & 7) == 7)
              ? __hip_atomic_load(fp, __ATOMIC_RELAXED, __HIP_MEMORY_SCOPE_AGENT)
              : ld_sc0(fp);
          if (__ballot(lane >= 16 && lane < 32 && v < (unsigned)(t + 1)) == 0ull) break;
        }
      } else {
        for (;;) {
          unsigned v = __hip_atomic_load(fp, __ATOMIC_RELAXED, __HIP_MEMORY_SCOPE_AGENT);
          if (__ballot(lane >= 16 && lane < 32 && v < (unsigned)(t + 1)) == 0ull) break;
        }
      }
      // stage upper half of h(t+1): stays in flight until the counted vmcnt
      if (fast) {
#pragma unroll
        for (int j = 0; j < 4; ++j) {
          int m = w * 4 + j;
          gl_lds16_l2(hsrcN + m * 1024 + 512 + ((lane ^ (m & 7)) * 8),
                      (unsigned short*)(At + m * 2048 + 1024));
        }
      } else {
#pragma unroll
        for (int j = 0; j < 4; ++j) {
          int m = w * 4 + j;
          gl_lds16_coh(hsrcN + m * 1024 + 512 + ((lane ^ (m & 7)) * 8),
                       (unsigned short*)(At + m * 2048 + 1024));
        }
      }
      asm volatile("" ::: "memory");
    }
  }
}

extern "C" void kernel_launch(void* const* d_in, const int* in_sizes, int n_in,
                              void* d_out, int out_size, void* d_ws, size_t ws_size,
                              hipStream_t stream) {
  const float* facts     = (const float*)d_in[0]; // [128][128][1024]
  const int*   num_facts = (const int*)d_in[1];   // [128]
  const float* g         = (const float*)d_in[2]; // [128][128][1]
  const float* mem_old   = (const float*)d_in[3]; // [128][1][1024]
  const float* Wr        = (const float*)d_in[4]; // [1024][1024]
  const float* Urw       = (const float*)d_in[5];
  const float* Urb       = (const float*)d_in[6];
  const float* W         = (const float*)d_in[7];
  const float* Uw        = (const float*)d_in[8];
  const float* Ub        = (const float*)d_in[9];

  // workspace layout (f16 elements unless noted)
  unsigned short* facts_h = (unsigned short*)d_ws;        // 16,777,216
  unsigned short* wstack  = facts_h + 16777216;           //  2,097,152 ([Wr|W])
  unsigned short* fwx     = wstack + 2097152;             // 33,554,432 ([t][b][2048])
  unsigned short* hbf     = fwx + 33554432;               //    262,144 (2 x [128][1024])
  unsigned int*   flg     = (unsigned int*)(hbf + 262144);// 8*32*32 u32 = 32KB
  unsigned int*   xcc     = flg + 8192;                   // 8*32*32 u32 = 32KB
  float* out = (float*)d_out;

  hipMemsetAsync(flg, 0, 2 * 8 * 32 * 32 * 4, stream);    // flg + xcc
  cvt_all<<<4096, 256, 0, stream>>>(
      (const float4*)facts,   (ushort4*)facts_h,
      (const float4*)Wr,      (ushort4*)wstack,
      (const float4*)W,       (ushort4*)(wstack + 1048576),
      (const float4*)mem_old, (ushort4*)hbf);
  gemm_fw<<<dim3(128, 16), 256, 0, stream>>>(facts_h, wstack, fwx);
  gru_recur<<<256, 256, 0, stream>>>(fwx, Urw, Urb, Uw, Ub, g, mem_old, num_facts, hbf, flg, xcc, out);
}

// Round 4
// 625.339 us; speedup vs baseline: 1.1252x; 1.0607x over previous
//
#include <hip/hip_runtime.h>
#include <stdint.h>

#define AS1 __attribute__((address_space(1)))
#define AS3 __attribute__((address_space(3)))

typedef _Float16 f16x8 __attribute__((ext_vector_type(8)));
typedef float f32x4 __attribute__((ext_vector_type(4)));

__device__ __forceinline__ unsigned short f32_f16(float f) {
  union { _Float16 h; unsigned short u; } v; v.h = (_Float16)f; return v.u;
}
__device__ __forceinline__ float f16_f32(unsigned short u) {
  union { _Float16 h; unsigned short u; } v; v.u = u; return (float)v.h;
}
// plain staging (L1+L2 cached) — for the GEMM
__device__ __forceinline__ void gl_lds16(const unsigned short* g, unsigned short* l) {
  __builtin_amdgcn_global_load_lds((const AS1 unsigned int*)g, (AS3 unsigned int*)l, 16, 0, 0);
}
// coherent staging — bypass L1+L2, read the Infinity Cache (R6/R9-proven)
__device__ __forceinline__ void gl_lds16_coh(const unsigned short* g, unsigned short* l) {
  __builtin_amdgcn_global_load_lds((const AS1 unsigned int*)g, (AS3 unsigned int*)l, 16, 0, 17);
}
// L2 staging — bypass L1 only (fast path: reads own-XCD L2)
__device__ __forceinline__ void gl_lds16_l2(const unsigned short* g, unsigned short* l) {
  __builtin_amdgcn_global_load_lds((const AS1 unsigned int*)g, (AS3 unsigned int*)l, 16, 0, 1);
}
// sc0 scalar load: bypass L1, read own-XCD L2 (R10-proven instruction)
__device__ __forceinline__ unsigned ld_sc0(const unsigned* p) {
  unsigned v;
  asm volatile("global_load_dword %0, %1, off sc0\n\ts_waitcnt vmcnt(0)"
               : "=v"(v) : "v"(p) : "memory");
  return v;
}
// sc0 store: write through L1 to own-XCD L2, leave line valid there (proven)
__device__ __forceinline__ void st_sc0(unsigned* p, unsigned v) {
  asm volatile("global_store_dword %0, %1, off sc0" :: "v"(p), "v"(v) : "memory");
}

// ---------------- fused f32 -> fp16 conversion (facts, Wr, W, mem_old) ----------
__global__ void cvt_all(const float4* __restrict__ sf, ushort4* __restrict__ df,
                        const float4* __restrict__ s1, ushort4* __restrict__ d1,
                        const float4* __restrict__ s2, ushort4* __restrict__ d2,
                        const float4* __restrict__ sm, ushort4* __restrict__ dm) {
  int i = blockIdx.x * blockDim.x + threadIdx.x;
  int st = gridDim.x * blockDim.x;
  for (int k = i; k < 4751360; k += st) {
    const float4* s; ushort4* d; int off;
    if (k < 4194304)      { s = sf; d = df; off = k; }
    else if (k < 4456448) { s = s1; d = d1; off = k - 4194304; }
    else if (k < 4718592) { s = s2; d = d2; off = k - 4456448; }
    else                  { s = sm; d = dm; off = k - 4718592; }
    float4 v = s[off];
    ushort4 o;
    o.x = f32_f16(v.x); o.y = f32_f16(v.y); o.z = f32_f16(v.z); o.w = f32_f16(v.w);
    d[off] = o;
  }
}

// ---------------- phase 1: C[t][b][0:2048] = facts(b,t,:) @ [Wr|W]^T (fp16 out) ----
// BK=64 (16 K-tiles), XOR source-swizzle staging, scalar C-store (proven R9/R11).
__global__ __launch_bounds__(256, 2) void gemm_fw(
    const unsigned short* __restrict__ A,
    const unsigned short* __restrict__ Bt,
    unsigned short* __restrict__ Ct)
{
  __shared__ __align__(16) unsigned short As[128 * 64];
  __shared__ __align__(16) unsigned short Bs[128 * 64];
  const int tid = threadIdx.x;
  const int lane = tid & 63;
  const int wv = tid >> 6;
  const int q = lane >> 4, ln = lane & 15;
  const int bm = blockIdx.x, bn = blockIdx.y;
  const int wm = (wv >> 1) * 64, wn = (wv & 1) * 64;

  f32x4 acc[4][4] = {};

  for (int kt = 0; kt < 1024; kt += 64) {
    __syncthreads();
#pragma unroll
    for (int rr = 0; rr < 4; ++rr) {
      int chunk = rr * 256 + tid;          // 0..1023
      int r = chunk >> 3, c = chunk & 7;   // 8 chunks (16B) per 128B row
      int cs = c ^ (r & 7);                // source chunk for this LDS pos
      gl_lds16(A + (size_t)(bm * 128 + r) * 1024 + kt + cs * 8, As + chunk * 8);
      gl_lds16(Bt + (size_t)(bn * 128 + r) * 1024 + kt + cs * 8, Bs + chunk * 8);
    }
    __syncthreads();
    f16x8 af[4][2], bfr[4][2];
#pragma unroll
    for (int mi = 0; mi < 4; ++mi)
#pragma unroll
      for (int kk = 0; kk < 2; ++kk)
        af[mi][kk] = *(const f16x8*)(As + (wm + mi * 16 + ln) * 64 + (((q + 4 * kk) ^ (ln & 7)) * 8));
#pragma unroll
    for (int ni = 0; ni < 4; ++ni)
#pragma unroll
      for (int kk = 0; kk < 2; ++kk)
        bfr[ni][kk] = *(const f16x8*)(Bs + (wn + ni * 16 + ln) * 64 + (((q + 4 * kk) ^ (ln & 7)) * 8));
#pragma unroll
    for (int kk = 0; kk < 2; ++kk)
#pragma unroll
      for (int mi = 0; mi < 4; ++mi)
#pragma unroll
        for (int ni = 0; ni < 4; ++ni)
          acc[mi][ni] = __builtin_amdgcn_mfma_f32_16x16x32_f16(af[mi][kk], bfr[ni][kk], acc[mi][ni], 0, 0, 0);
  }
#pragma unroll
  for (int mi = 0; mi < 4; ++mi)
#pragma unroll
    for (int ni = 0; ni < 4; ++ni)
#pragma unroll
      for (int r2 = 0; r2 < 4; ++r2) {
        int trow = wm + mi * 16 + q * 4 + r2;   // == t
        int col = bn * 128 + wn + ni * 16 + ln; // 0..2047: [fWr | fW]
        Ct[(size_t)trow * 262144 + (size_t)bm * 2048 + col] = f32_f16(acc[mi][ni][r2]);
      }
}

// ---------------- phase 2: the recurrence (single-poll pipelined split-K) ----
// Grid 256 = 8 groups x 32 dim-slices; 4 waves, one matrix per wave-pair.
// R3 post-mortem: vmcnt(N) waits on the OLDEST ops, so any sc0-poll after
// issuing staging force-drains it -> the poll must precede ALL staging issue.
// Structure per step: [bottom of t] flag -> single poll of all 32 flags ->
// issue staging lower(4)+upper(4) -> issue 12 fwx(t+1) prefetches (raw u16,
// converted at use) -> counted vmcnt(16|4) drains ONLY lower -> raw s_barrier.
// [top of t+1] MFMA-lower runs while upper staging + fwx return; vmcnt(12|0) +
// raw barrier; MFMA-upper. Upper-staging latency hides under MFMA-lower.
// sched_barrier(0) pins issue order so the counted-wait arithmetic holds.
__global__ __launch_bounds__(256, 1) void gru_recur(
    const unsigned short* __restrict__ fwx,   // [128 t][128 b][2048] f16
    const float* __restrict__ Urw, const float* __restrict__ Urb,
    const float* __restrict__ Uw,  const float* __restrict__ Ub,
    const float* __restrict__ g,              // [128 b][128 t]
    const float* __restrict__ mem_old,        // [128][1024]
    const int* __restrict__ nfp,              // [128]
    unsigned short* __restrict__ hbf,         // [2][128][1024] f16
    unsigned int* __restrict__ flg,           // [8 ga][32 blk][32 pad] u32
    unsigned int* __restrict__ xcc,           // [8 ga][32 blk][32 pad] u32
    float* __restrict__ out)                  // [128][1024] f32
{
  __shared__ __align__(16) unsigned char At[32768]; // 16 rows x 2048B, dense
  __shared__ float xchg[512];
  __shared__ int fast_lds;

  const int tid = threadIdx.x;
  const int lane = tid & 63;
  const int w = tid >> 6;
  const int q = lane >> 4;
  const int ln = lane & 15;
  const int matrix = w >> 1;
  const int ntile = w & 1;
  const int ga = blockIdx.x & 7;    // XCD-local group under round-robin dispatch
  const int dsl = blockIdx.x >> 3;  // dim-slice within group, 0..31
  const int b0 = ga * 16;
  const int n_g = dsl * 32 + ntile * 16 + ln;

  // --- XCD-uniformity handshake (R10-proven, over the always-correct IC path) ---
  unsigned my_xcc;
  asm("s_getreg_b32 %0, hwreg(HW_REG_XCC_ID)" : "=s"(my_xcc));
  if (tid == 0)
    __hip_atomic_store(&xcc[(ga * 32 + dsl) * 32], my_xcc + 1u,
                       __ATOMIC_RELAXED, __HIP_MEMORY_SCOPE_AGENT);
  if (w == 0) {
    unsigned* xp = &xcc[(ga * 32 + (lane & 31)) * 32];
    unsigned v;
    for (;;) {
      v = __hip_atomic_load(xp, __ATOMIC_RELAXED, __HIP_MEMORY_SCOPE_AGENT);
      if (__ballot(lane < 32 && v == 0u) == 0ull) break;
    }
    unsigned long long bad = __ballot(lane < 32 && v != my_xcc + 1u);
    if (lane == 0) fast_lds = (bad == 0ull);
  }

  // --- one-time: weights into registers (B-fragment layout: n=lane&15, k=q*8+j) ---
  const float* Wm = matrix ? Uw : Urw;
  f16x8 bw[32];
#pragma unroll
  for (int ks = 0; ks < 32; ++ks) {
    const float* s = Wm + (size_t)n_g * 1024 + ks * 32 + q * 8;
    float4 x0 = *(const float4*)s;
    float4 x1 = *(const float4*)(s + 4);
    f16x8 t;
    t[0] = (_Float16)x0.x; t[1] = (_Float16)x0.y;
    t[2] = (_Float16)x0.z; t[3] = (_Float16)x0.w;
    t[4] = (_Float16)x1.x; t[5] = (_Float16)x1.y;
    t[6] = (_Float16)x1.z; t[7] = (_Float16)x1.w;
    bw[ks] = t;
  }
  const float bias = (matrix ? Ub : Urb)[n_g];
  const f32x4 zero4 = {0.f, 0.f, 0.f, 0.f};
  f32x4 acc0 = {bias, bias, bias, bias};   // even-ks chain (carries the bias)
  f32x4 acc1 = zero4;                      // odd-ks chain

  float h_own[4] = {0.f, 0.f, 0.f, 0.f};
  int nf[4] = {0, 0, 0, 0};
  if (matrix == 0) {
#pragma unroll
    for (int r = 0; r < 4; ++r) {
      int b = b0 + q * 4 + r;
      h_own[r] = mem_old[(size_t)b * 1024 + n_g];
      nf[r] = nfp[b];
    }
  }

  __syncthreads();
  const int fast = fast_lds;

  // A-fragment read bases: row ln, chunk(ks) = (q + 4*ks) ^ (ln&7).
  const int swz = ln & 7;
  const int rowb = ln * 2048 + (q ^ (swz & 3)) * 16;
  const int be = rowb + ((swz >> 2) << 6);        // ks even
  const int bo = rowb + (((swz >> 2) ^ 1) << 6);  // ks odd

  // epilogue operands carried as RAW u16 (no cvt at issue -> loads stay in flight)
  unsigned short fwru[4] = {0, 0, 0, 0}, fwu[4] = {0, 0, 0, 0};
  float gvv[4] = {0.f, 0.f, 0.f, 0.f};

  // --- prologue: mirror of the loop bottom for t=0 (h(0)=mem_old via cvt_all) ---
  {
    const unsigned short* hsrc = hbf + (size_t)b0 * 1024;
    if (fast) {
#pragma unroll
      for (int j = 0; j < 4; ++j) {
        int m = w * 4 + j;
        gl_lds16_l2(hsrc + m * 1024 + ((lane ^ (m & 7)) * 8),
                    (unsigned short*)(At + m * 2048));
      }
      __builtin_amdgcn_sched_barrier(0);
#pragma unroll
      for (int j = 0; j < 4; ++j) {
        int m = w * 4 + j;
        gl_lds16_l2(hsrc + m * 1024 + 512 + ((lane ^ (m & 7)) * 8),
                    (unsigned short*)(At + m * 2048 + 1024));
      }
    } else {
#pragma unroll
      for (int j = 0; j < 4; ++j) {
        int m = w * 4 + j;
        gl_lds16_coh(hsrc + m * 1024 + ((lane ^ (m & 7)) * 8),
                     (unsigned short*)(At + m * 2048));
      }
      __builtin_amdgcn_sched_barrier(0);
#pragma unroll
      for (int j = 0; j < 4; ++j) {
        int m = w * 4 + j;
        gl_lds16_coh(hsrc + m * 1024 + 512 + ((lane ^ (m & 7)) * 8),
                     (unsigned short*)(At + m * 2048 + 1024));
      }
    }
    __builtin_amdgcn_sched_barrier(0);
    if (matrix == 0) {
#pragma unroll
      for (int r = 0; r < 4; ++r) {
        int b = b0 + q * 4 + r;
        size_t base = (size_t)b * 2048;   // t = 0
        fwru[r] = fwx[base + n_g];
        fwu[r]  = fwx[base + 1024 + n_g];
        gvv[r]  = g[b * 128 + 0];
      }
    }
    __builtin_amdgcn_sched_barrier(0);
    if (matrix == 0) asm volatile("s_waitcnt vmcnt(16)" ::: "memory");
    else             asm volatile("s_waitcnt vmcnt(4)"  ::: "memory");
    __builtin_amdgcn_sched_barrier(0);
    __builtin_amdgcn_s_barrier();
    __builtin_amdgcn_sched_barrier(0);
    asm volatile("" ::: "memory");
  }

  for (int t = 0; t < 128; ++t) {
    // entry invariant: lower half of At(t) in LDS (all waves counted-drained
    // before the bottom barrier); upper staging (+12 fwx for matrix0) in flight.

    // MFMA lower half: ks 0..15 (dims 0..511), 2 independent chains
#pragma unroll
    for (int ks = 0; ks < 16; ++ks) {
      const unsigned char* ap = At + (((ks & 1) ? bo : be) + ((ks >> 1) << 7));
      f16x8 a = *(const f16x8*)ap;
      if (ks & 1) acc1 = __builtin_amdgcn_mfma_f32_16x16x32_f16(a, bw[ks], acc1, 0, 0, 0);
      else        acc0 = __builtin_amdgcn_mfma_f32_16x16x32_f16(a, bw[ks], acc0, 0, 0, 0);
    }

    // upper half ready: drain the 4 upper-stage loads (oldest); matrix0 keeps
    // its 12 fwx prefetches (youngest) in flight.
    __builtin_amdgcn_sched_barrier(0);
    if (matrix == 0) asm volatile("s_waitcnt vmcnt(12)" ::: "memory");
    else             asm volatile("s_waitcnt vmcnt(0)" ::: "memory");
    __builtin_amdgcn_sched_barrier(0);
    __builtin_amdgcn_s_barrier();
    __builtin_amdgcn_sched_barrier(0);
    asm volatile("" ::: "memory");

    // MFMA upper half: ks 16..31 (dims 512..1023)
#pragma unroll
    for (int ks = 16; ks < 32; ++ks) {
      const unsigned char* ap = At + (((ks & 1) ? bo : be) + ((ks >> 1) << 7));
      f16x8 a = *(const f16x8*)ap;
      if (ks & 1) acc1 = __builtin_amdgcn_mfma_f32_16x16x32_f16(a, bw[ks], acc1, 0, 0, 0);
      else        acc0 = __builtin_amdgcn_mfma_f32_16x16x32_f16(a, bw[ks], acc0, 0, 0, 0);
    }

    if (matrix == 1) { // u = U h + U_b -> exchange to r-side waves
#pragma unroll
      for (int r = 0; r < 4; ++r)
        xchg[ntile * 256 + (q * 4 + r) * 16 + ln] = acc0[r] + acc1[r];
    }
    __syncthreads();
    if (matrix == 0) {
      unsigned int* hb32 = (unsigned int*)(hbf + (size_t)((t + 1) & 1) * 131072);
#pragma unroll
      for (int r = 0; r < 4; ++r) {
        float u = xchg[ntile * 256 + (q * 4 + r) * 16 + ln];
        float rv = acc0[r] + acc1[r] + f16_f32(fwru[r]);
        float rg = 1.0f / (1.0f + __expf(-rv));
        float pre = f16_f32(fwu[r]) + rg * u;
        float e2 = __expf(-2.0f * fabsf(pre));
        float th = (1.0f - e2) / (1.0f + e2);
        float ht = copysignf(th, pre);
        float hn = gvv[r] * ht + (1.0f - gvv[r]) * h_own[r];
        h_own[r] = hn;
        int b = b0 + q * 4 + r;
        // pack adjacent dims (n_g even|odd) into u32
        unsigned short hu = f32_f16(hn);
        unsigned short pu = (unsigned short)__shfl_xor((int)hu, 1, 64);
        if (!(ln & 1)) {
          unsigned val = (unsigned)hu | ((unsigned)pu << 16);
          unsigned* dst = &hb32[(b * 1024 + n_g) >> 1];
          if (fast) st_sc0(dst, val);                          // write-through to own-XCD L2
          else __hip_atomic_store(dst, val, __ATOMIC_RELAXED,  // write-through to IC
                                  __HIP_MEMORY_SCOPE_AGENT);
        }
        if (t == nf[r] - 1) out[(size_t)b * 1024 + n_g] = hn;
      }
    }
    acc0[0] = bias; acc0[1] = bias; acc0[2] = bias; acc0[3] = bias;
    acc1 = zero4;

    __syncthreads(); // all waves' h stores drained (compiler vmcnt(0) + barrier);
                     // also: all waves finished reading At(t)

    if (t < 127) {
      if (tid == 0) {
        if (fast) {
          asm volatile("s_waitcnt vmcnt(0)" ::: "memory"); // belt & braces
          st_sc0(&flg[(ga * 32 + dsl) * 32], (unsigned)(t + 1));
        } else {
          __hip_atomic_store(&flg[(ga * 32 + dsl) * 32], (unsigned)(t + 1),
                             __ATOMIC_RELAXED, __HIP_MEMORY_SCOPE_AGENT);
        }
      }

      // SINGLE poll of all 32 producers, BEFORE any staging issue (all waves;
      // nothing in flight here, so the poll's inline vmcnt(0) is free)
      unsigned int* fp = &flg[(ga * 32 + (lane & 31)) * 32];
      if (fast) {
        for (int it = 0;; ++it) {
          unsigned v = ((it & 7) == 7)
              ? __hip_atomic_load(fp, __ATOMIC_RELAXED, __HIP_MEMORY_SCOPE_AGENT)
              : ld_sc0(fp);
          if (__ballot(lane < 32 && v < (unsigned)(t + 1)) == 0ull) break;
        }
      } else {
        for (;;) {
          unsigned v = __hip_atomic_load(fp, __ATOMIC_RELAXED, __HIP_MEMORY_SCOPE_AGENT);
          if (__ballot(lane < 32 && v < (unsigned)(t + 1)) == 0ull) break;
        }
      }

      // stage h(t+1): lower 4 rows' halves first, then upper (order pinned —
      // the counted waits below rely on lower being the oldest outstanding)
      const unsigned short* hsrcN = hbf + (size_t)((t + 1) & 1) * 131072 + (size_t)b0 * 1024;
      if (fast) {
#pragma unroll
        for (int j = 0; j < 4; ++j) {
          int m = w * 4 + j;
          gl_lds16_l2(hsrcN + m * 1024 + ((lane ^ (m & 7)) * 8),
                      (unsigned short*)(At + m * 2048));
        }
        __builtin_amdgcn_sched_barrier(0);
#pragma unroll
        for (int j = 0; j < 4; ++j) {
          int m = w * 4 + j;
          gl_lds16_l2(hsrcN + m * 1024 + 512 + ((lane ^ (m & 7)) * 8),
                      (unsigned short*)(At + m * 2048 + 1024));
        }
      } else {
#pragma unroll
        for (int j = 0; j < 4; ++j) {
          int m = w * 4 + j;
          gl_lds16_coh(hsrcN + m * 1024 + ((lane ^ (m & 7)) * 8),
                       (unsigned short*)(At + m * 2048));
        }
        __builtin_amdgcn_sched_barrier(0);
#pragma unroll
        for (int j = 0; j < 4; ++j) {
          int m = w * 4 + j;
          gl_lds16_coh(hsrcN + m * 1024 + 512 + ((lane ^ (m & 7)) * 8),
                       (unsigned short*)(At + m * 2048 + 1024));
        }
      }
      __builtin_amdgcn_sched_barrier(0);

      // fwx/g prefetch for t+1 (raw u16/f32, converted at use next iteration)
      if (matrix == 0) {
#pragma unroll
        for (int r = 0; r < 4; ++r) {
          int b = b0 + q * 4 + r;
          size_t base = (size_t)(t + 1) * 262144 + (size_t)b * 2048;
          fwru[r] = fwx[base + n_g];
          fwu[r]  = fwx[base + 1024 + n_g];
          gvv[r]  = g[b * 128 + (t + 1)];
        }
      }
      __builtin_amdgcn_sched_barrier(0);

      // drain ONLY the lower staging (oldest 4); upper + fwx ride into t+1
      if (matrix == 0) asm volatile("s_waitcnt vmcnt(16)" ::: "memory");
      else             asm volatile("s_waitcnt vmcnt(4)"  ::: "memory");
      __builtin_amdgcn_sched_barrier(0);
      __builtin_amdgcn_s_barrier();
      __builtin_amdgcn_sched_barrier(0);
      asm volatile("" ::: "memory");
    }
  }
}

extern "C" void kernel_launch(void* const* d_in, const int* in_sizes, int n_in,
                              void* d_out, int out_size, void* d_ws, size_t ws_size,
                              hipStream_t stream) {
  const float* facts     = (const float*)d_in[0]; // [128][128][1024]
  const int*   num_facts = (const int*)d_in[1];   // [128]
  const float* g         = (const float*)d_in[2]; // [128][128][1]
  const float* mem_old   = (const float*)d_in[3]; // [128][1][1024]
  const float* Wr        = (const float*)d_in[4]; // [1024][1024]
  const float* Urw       = (const float*)d_in[5];
  const float* Urb       = (const float*)d_in[6];
  const float* W         = (const float*)d_in[7];
  const float* Uw        = (const float*)d_in[8];
  const float* Ub        = (const float*)d_in[9];

  // workspace layout (f16 elements unless noted)
  unsigned short* facts_h = (unsigned short*)d_ws;        // 16,777,216
  unsigned short* wstack  = facts_h + 16777216;           //  2,097,152 ([Wr|W])
  unsigned short* fwx     = wstack + 2097152;             // 33,554,432 ([t][b][2048])
  unsigned short* hbf     = fwx + 33554432;               //    262,144 (2 x [128][1024])
  unsigned int*   flg     = (unsigned int*)(hbf + 262144);// 8*32*32 u32 = 32KB
  unsigned int*   xcc     = flg + 8192;                   // 8*32*32 u32 = 32KB
  float* out = (float*)d_out;

  hipMemsetAsync(flg, 0, 2 * 8 * 32 * 32 * 4, stream);    // flg + xcc
  cvt_all<<<4096, 256, 0, stream>>>(
      (const float4*)facts,   (ushort4*)facts_h,
      (const float4*)Wr,      (ushort4*)wstack,
      (const float4*)W,       (ushort4*)(wstack + 1048576),
      (const float4*)mem_old, (ushort4*)hbf);
  gemm_fw<<<dim3(128, 16), 256, 0, stream>>>(facts_h, wstack, fwx);
  gru_recur<<<256, 256, 0, stream>>>(fwx, Urw, Urb, Uw, Ub, g, mem_old, num_facts, hbf, flg, xcc, out);
}

// Round 5
// 571.277 us; speedup vs baseline: 1.2317x; 1.0946x over previous
//
#include <hip/hip_runtime.h>
#include <stdint.h>

#define AS1 __attribute__((address_space(1)))
#define AS3 __attribute__((address_space(3)))

typedef _Float16 f16x8 __attribute__((ext_vector_type(8)));
typedef float f32x4 __attribute__((ext_vector_type(4)));

__device__ __forceinline__ unsigned short f32_f16(float f) {
  union { _Float16 h; unsigned short u; } v; v.h = (_Float16)f; return v.u;
}
__device__ __forceinline__ float f16_f32(unsigned short u) {
  union { _Float16 h; unsigned short u; } v; v.u = u; return (float)v.h;
}
// plain staging (L1+L2 cached) — for the GEMM
__device__ __forceinline__ void gl_lds16(const unsigned short* g, unsigned short* l) {
  __builtin_amdgcn_global_load_lds((const AS1 unsigned int*)g, (AS3 unsigned int*)l, 16, 0, 0);
}
// coherent staging — bypass L1+L2, read the Infinity Cache (R6/R9-proven)
__device__ __forceinline__ void gl_lds16_coh(const unsigned short* g, unsigned short* l) {
  __builtin_amdgcn_global_load_lds((const AS1 unsigned int*)g, (AS3 unsigned int*)l, 16, 0, 17);
}
// L2 staging — bypass L1 only (fast path: reads own-XCD L2)
__device__ __forceinline__ void gl_lds16_l2(const unsigned short* g, unsigned short* l) {
  __builtin_amdgcn_global_load_lds((const AS1 unsigned int*)g, (AS3 unsigned int*)l, 16, 0, 1);
}
// sc0 scalar load: bypass L1, read own-XCD L2 (R10-proven instruction)
__device__ __forceinline__ unsigned ld_sc0(const unsigned* p) {
  unsigned v;
  asm volatile("global_load_dword %0, %1, off sc0\n\ts_waitcnt vmcnt(0)"
               : "=v"(v) : "v"(p) : "memory");
  return v;
}
// sc0 store: write through L1 to own-XCD L2, leave line valid there (proven)
__device__ __forceinline__ void st_sc0(unsigned* p, unsigned v) {
  asm volatile("global_store_dword %0, %1, off sc0" :: "v"(p), "v"(v) : "memory");
}

// ---------------- fused f32 -> fp16 conversion (facts, Wr, W, mem_old) ----------
__global__ void cvt_all(const float4* __restrict__ sf, ushort4* __restrict__ df,
                        const float4* __restrict__ s1, ushort4* __restrict__ d1,
                        const float4* __restrict__ s2, ushort4* __restrict__ d2,
                        const float4* __restrict__ sm, ushort4* __restrict__ dm) {
  int i = blockIdx.x * blockDim.x + threadIdx.x;
  int st = gridDim.x * blockDim.x;
  for (int k = i; k < 4751360; k += st) {
    const float4* s; ushort4* d; int off;
    if (k < 4194304)      { s = sf; d = df; off = k; }
    else if (k < 4456448) { s = s1; d = d1; off = k - 4194304; }
    else if (k < 4718592) { s = s2; d = d2; off = k - 4456448; }
    else                  { s = sm; d = dm; off = k - 4718592; }
    float4 v = s[off];
    ushort4 o;
    o.x = f32_f16(v.x); o.y = f32_f16(v.y); o.z = f32_f16(v.z); o.w = f32_f16(v.w);
    d[off] = o;
  }
}

// ---------------- phase 1: C[t][b][0:2048] = facts(b,t,:) @ [Wr|W]^T (fp16 out) ----
// BK=64 (16 K-tiles), XOR source-swizzle staging, scalar C-store (proven R9/R11).
__global__ __launch_bounds__(256, 2) void gemm_fw(
    const unsigned short* __restrict__ A,
    const unsigned short* __restrict__ Bt,
    unsigned short* __restrict__ Ct)
{
  __shared__ __align__(16) unsigned short As[128 * 64];
  __shared__ __align__(16) unsigned short Bs[128 * 64];
  const int tid = threadIdx.x;
  const int lane = tid & 63;
  const int wv = tid >> 6;
  const int q = lane >> 4, ln = lane & 15;
  const int bm = blockIdx.x, bn = blockIdx.y;
  const int wm = (wv >> 1) * 64, wn = (wv & 1) * 64;

  f32x4 acc[4][4] = {};

  for (int kt = 0; kt < 1024; kt += 64) {
    __syncthreads();
#pragma unroll
    for (int rr = 0; rr < 4; ++rr) {
      int chunk = rr * 256 + tid;          // 0..1023
      int r = chunk >> 3, c = chunk & 7;   // 8 chunks (16B) per 128B row
      int cs = c ^ (r & 7);                // source chunk for this LDS pos
      gl_lds16(A + (size_t)(bm * 128 + r) * 1024 + kt + cs * 8, As + chunk * 8);
      gl_lds16(Bt + (size_t)(bn * 128 + r) * 1024 + kt + cs * 8, Bs + chunk * 8);
    }
    __syncthreads();
    f16x8 af[4][2], bfr[4][2];
#pragma unroll
    for (int mi = 0; mi < 4; ++mi)
#pragma unroll
      for (int kk = 0; kk < 2; ++kk)
        af[mi][kk] = *(const f16x8*)(As + (wm + mi * 16 + ln) * 64 + (((q + 4 * kk) ^ (ln & 7)) * 8));
#pragma unroll
    for (int ni = 0; ni < 4; ++ni)
#pragma unroll
      for (int kk = 0; kk < 2; ++kk)
        bfr[ni][kk] = *(const f16x8*)(Bs + (wn + ni * 16 + ln) * 64 + (((q + 4 * kk) ^ (ln & 7)) * 8));
#pragma unroll
    for (int kk = 0; kk < 2; ++kk)
#pragma unroll
      for (int mi = 0; mi < 4; ++mi)
#pragma unroll
        for (int ni = 0; ni < 4; ++ni)
          acc[mi][ni] = __builtin_amdgcn_mfma_f32_16x16x32_f16(af[mi][kk], bfr[ni][kk], acc[mi][ni], 0, 0, 0);
  }
#pragma unroll
  for (int mi = 0; mi < 4; ++mi)
#pragma unroll
    for (int ni = 0; ni < 4; ++ni)
#pragma unroll
      for (int r2 = 0; r2 < 4; ++r2) {
        int trow = wm + mi * 16 + q * 4 + r2;   // == t
        int col = bn * 128 + wn + ni * 16 + ln; // 0..2047: [fWr | fW]
        Ct[(size_t)trow * 262144 + (size_t)bm * 2048 + col] = f32_f16(acc[mi][ni][r2]);
      }
}

// ---------------- phase 2: the recurrence (short-chain rendezvous) ----
// Grid 256 = 8 groups x 32 dim-slices; 4 waves, one matrix per wave-pair.
// R4 post-mortem: per-step floor is the serial chain {store-ack -> flag ->
// visibility -> poll -> stage -> drain}, not MFMA/VALU. This version cuts it:
//  * per-PRODUCER-WAVE flags (64/group): each m0 wave drains only its own 4
//    stores (vmcnt(0)) and flags immediately — no block barrier, no tid0 hop.
//  * 2 raw s_barriers/step (A: xchg handoff; B: post-stage) instead of 4.
//  * fwx(t+1) issued AFTER staging: vmcnt(12) drains staging only; fwx rides
//    through barrier B + MFMA phase, consumed in the next epilogue — off the
//    flag path and off the poll path.
//  * 4-way acc chains (ks&3): MFMA phase issue-bound.
// Coherence flavors (sc0 fast path / IC-atomic fallback) unchanged, R10-proven.
__global__ __launch_bounds__(256, 1) void gru_recur(
    const unsigned short* __restrict__ fwx,   // [128 t][128 b][2048] f16
    const float* __restrict__ Urw, const float* __restrict__ Urb,
    const float* __restrict__ Uw,  const float* __restrict__ Ub,
    const float* __restrict__ g,              // [128 b][128 t]
    const float* __restrict__ mem_old,        // [128][1024]
    const int* __restrict__ nfp,              // [128]
    unsigned short* __restrict__ hbf,         // [2][128][1024] f16
    unsigned int* __restrict__ flg,           // [8 ga][32 blk][2 wave][16 pad] u32
    unsigned int* __restrict__ xcc,           // [8 ga][32 blk][32 pad] u32
    float* __restrict__ out)                  // [128][1024] f32
{
  __shared__ __align__(16) unsigned char At[32768]; // 16 rows x 2048B, dense
  __shared__ float xchg[512];
  __shared__ int fast_lds;

  const int tid = threadIdx.x;
  const int lane = tid & 63;
  const int w = tid >> 6;
  const int q = lane >> 4;
  const int ln = lane & 15;
  const int matrix = w >> 1;
  const int ntile = w & 1;
  const int ga = blockIdx.x & 7;    // XCD-local group under round-robin dispatch
  const int dsl = blockIdx.x >> 3;  // dim-slice within group, 0..31
  const int b0 = ga * 16;
  const int n_g = dsl * 32 + ntile * 16 + ln;

  // --- XCD-uniformity handshake (R10-proven, over the always-correct IC path) ---
  unsigned my_xcc;
  asm("s_getreg_b32 %0, hwreg(HW_REG_XCC_ID)" : "=s"(my_xcc));
  if (tid == 0)
    __hip_atomic_store(&xcc[(ga * 32 + dsl) * 32], my_xcc + 1u,
                       __ATOMIC_RELAXED, __HIP_MEMORY_SCOPE_AGENT);
  if (w == 0) {
    unsigned* xp = &xcc[(ga * 32 + (lane & 31)) * 32];
    unsigned v;
    for (;;) {
      v = __hip_atomic_load(xp, __ATOMIC_RELAXED, __HIP_MEMORY_SCOPE_AGENT);
      if (__ballot(lane < 32 && v == 0u) == 0ull) break;
    }
    unsigned long long bad = __ballot(lane < 32 && v != my_xcc + 1u);
    if (lane == 0) fast_lds = (bad == 0ull);
  }

  // --- one-time: weights into registers (B-fragment layout: n=lane&15, k=q*8+j) ---
  const float* Wm = matrix ? Uw : Urw;
  f16x8 bw[32];
#pragma unroll
  for (int ks = 0; ks < 32; ++ks) {
    const float* s = Wm + (size_t)n_g * 1024 + ks * 32 + q * 8;
    float4 x0 = *(const float4*)s;
    float4 x1 = *(const float4*)(s + 4);
    f16x8 t;
    t[0] = (_Float16)x0.x; t[1] = (_Float16)x0.y;
    t[2] = (_Float16)x0.z; t[3] = (_Float16)x0.w;
    t[4] = (_Float16)x1.x; t[5] = (_Float16)x1.y;
    t[6] = (_Float16)x1.z; t[7] = (_Float16)x1.w;
    bw[ks] = t;
  }
  const float bias = (matrix ? Ub : Urb)[n_g];
  const f32x4 zero4 = {0.f, 0.f, 0.f, 0.f};
  f32x4 acc0 = {bias, bias, bias, bias};   // ks%4==0 chain (carries the bias)
  f32x4 acc1 = zero4, acc2 = zero4, acc3 = zero4;

  float h_own[4] = {0.f, 0.f, 0.f, 0.f};
  int nf[4] = {0, 0, 0, 0};
  if (matrix == 0) {
#pragma unroll
    for (int r = 0; r < 4; ++r) {
      int b = b0 + q * 4 + r;
      h_own[r] = mem_old[(size_t)b * 1024 + n_g];
      nf[r] = nfp[b];
    }
  }

  __syncthreads();
  const int fast = fast_lds;

  // A-fragment read bases: row ln, chunk(ks) = (q + 4*ks) ^ (ln&7).
  const int swz = ln & 7;
  const int rowb = ln * 2048 + (q ^ (swz & 3)) * 16;
  const int be = rowb + ((swz >> 2) << 6);        // ks even
  const int bo = rowb + (((swz >> 2) ^ 1) << 6);  // ks odd

  // per-wave flag (producers = m0 waves); poll maps 64 lanes -> 64 flags
  unsigned int* myf = flg + ((size_t)((ga * 32 + dsl) * 2 + ntile)) * 16;
  unsigned int* fp  = flg + ((size_t)((ga * 32 + (lane >> 1)) * 2 + (lane & 1))) * 16;

  // epilogue operands carried as RAW u16 (loads stay in flight through barriers)
  unsigned short fwru[4] = {0, 0, 0, 0}, fwu[4] = {0, 0, 0, 0};
  float gvv[4] = {0.f, 0.f, 0.f, 0.f};

  // --- prologue: mirror of the loop bottom for t=0 (h(0)=mem_old via cvt_all) ---
  {
    const unsigned short* hsrc = hbf + (size_t)b0 * 1024;
    if (fast) {
#pragma unroll
      for (int j = 0; j < 8; ++j) {
        int blk = w * 8 + j;
        int m = blk >> 1, kh = blk & 1;
        gl_lds16_l2(hsrc + m * 1024 + kh * 512 + ((lane ^ (m & 7)) * 8),
                    (unsigned short*)(At + m * 2048 + kh * 1024));
      }
    } else {
#pragma unroll
      for (int j = 0; j < 8; ++j) {
        int blk = w * 8 + j;
        int m = blk >> 1, kh = blk & 1;
        gl_lds16_coh(hsrc + m * 1024 + kh * 512 + ((lane ^ (m & 7)) * 8),
                     (unsigned short*)(At + m * 2048 + kh * 1024));
      }
    }
    __builtin_amdgcn_sched_barrier(0);
    if (matrix == 0) {  // fwx(0): 12 loads, youngest — ride through the barrier
#pragma unroll
      for (int r = 0; r < 4; ++r) {
        int b = b0 + q * 4 + r;
        size_t base = (size_t)b * 2048;   // t = 0
        fwru[r] = fwx[base + n_g];
        fwu[r]  = fwx[base + 1024 + n_g];
        gvv[r]  = g[b * 128 + 0];
      }
    }
    __builtin_amdgcn_sched_barrier(0);
    if (matrix == 0) asm volatile("s_waitcnt vmcnt(12)" ::: "memory"); // drain 8 staging
    else             asm volatile("s_waitcnt vmcnt(0)"  ::: "memory");
    __builtin_amdgcn_sched_barrier(0);
    __builtin_amdgcn_s_barrier();
    __builtin_amdgcn_sched_barrier(0);
    asm volatile("" ::: "memory");
  }

  for (int t = 0; t < 128; ++t) {
    // entry invariant: At(t) fully staged (barrier B / prologue); fwx(t) in
    // flight or done (matrix0), consumed below with compiler-inserted waits.

    // MFMA: ks 0..31 from LDS, 4 independent chains
#pragma unroll
    for (int ks = 0; ks < 32; ++ks) {
      const unsigned char* ap = At + (((ks & 1) ? bo : be) + ((ks >> 1) << 7));
      f16x8 a = *(const f16x8*)ap;
      switch (ks & 3) {
        case 0: acc0 = __builtin_amdgcn_mfma_f32_16x16x32_f16(a, bw[ks], acc0, 0, 0, 0); break;
        case 1: acc1 = __builtin_amdgcn_mfma_f32_16x16x32_f16(a, bw[ks], acc1, 0, 0, 0); break;
        case 2: acc2 = __builtin_amdgcn_mfma_f32_16x16x32_f16(a, bw[ks], acc2, 0, 0, 0); break;
        default: acc3 = __builtin_amdgcn_mfma_f32_16x16x32_f16(a, bw[ks], acc3, 0, 0, 0); break;
      }
    }

    if (matrix == 1) { // u = U h + U_b -> hand off to r-side waves
#pragma unroll
      for (int r = 0; r < 4; ++r)
        xchg[ntile * 256 + (q * 4 + r) * 16 + ln] =
            (acc0[r] + acc1[r]) + (acc2[r] + acc3[r]);
    }
    // ---- barrier A: xchg written (lgkm drained); all At(t) reads complete ----
    asm volatile("s_waitcnt lgkmcnt(0)" ::: "memory");
    __builtin_amdgcn_sched_barrier(0);
    __builtin_amdgcn_s_barrier();
    __builtin_amdgcn_sched_barrier(0);
    asm volatile("" ::: "memory");

    if (matrix == 0) {
      unsigned int* hb32 = (unsigned int*)(hbf + (size_t)((t + 1) & 1) * 131072);
#pragma unroll
      for (int r = 0; r < 4; ++r) {
        float u = xchg[ntile * 256 + (q * 4 + r) * 16 + ln];
        float rv = (acc0[r] + acc1[r]) + (acc2[r] + acc3[r]) + f16_f32(fwru[r]);
        float rg = 1.0f / (1.0f + __expf(-rv));
        float pre = f16_f32(fwu[r]) + rg * u;
        float e2 = __expf(-2.0f * fabsf(pre));
        float th = (1.0f - e2) / (1.0f + e2);
        float ht = copysignf(th, pre);
        float hn = gvv[r] * ht + (1.0f - gvv[r]) * h_own[r];
        h_own[r] = hn;
        int b = b0 + q * 4 + r;
        // pack adjacent dims (n_g even|odd) into u32
        unsigned short hu = f32_f16(hn);
        unsigned short pu = (unsigned short)__shfl_xor((int)hu, 1, 64);
        if (!(ln & 1)) {
          unsigned val = (unsigned)hu | ((unsigned)pu << 16);
          unsigned* dst = &hb32[(b * 1024 + n_g) >> 1];
          if (fast) st_sc0(dst, val);                          // write-through to own-XCD L2
          else __hip_atomic_store(dst, val, __ATOMIC_RELAXED,  // write-through to IC
                                  __HIP_MEMORY_SCOPE_AGENT);
        }
        if (t == nf[r] - 1) out[(size_t)b * 1024 + n_g] = hn;
      }
      if (t < 127) {
        // drain ONLY this wave's stores (4 h + any out), then flag immediately
        __builtin_amdgcn_sched_barrier(0);
        asm volatile("s_waitcnt vmcnt(0)" ::: "memory");
        if (lane == 0) {
          if (fast) st_sc0(myf, (unsigned)(t + 1));
          else __hip_atomic_store(myf, (unsigned)(t + 1),
                                  __ATOMIC_RELAXED, __HIP_MEMORY_SCOPE_AGENT);
        }
      }
    }
    acc0[0] = bias; acc0[1] = bias; acc0[2] = bias; acc0[3] = bias;
    acc1 = zero4; acc2 = zero4; acc3 = zero4;

    if (t < 127) {
      // poll all 64 producer-wave flags (one per lane); all waves poll
      if (fast) {
        for (int it = 0;; ++it) {
          unsigned v = ((it & 7) == 7)
              ? __hip_atomic_load(fp, __ATOMIC_RELAXED, __HIP_MEMORY_SCOPE_AGENT)
              : ld_sc0(fp);
          if (__ballot(v < (unsigned)(t + 1)) == 0ull) break;
        }
      } else {
        for (;;) {
          unsigned v = __hip_atomic_load(fp, __ATOMIC_RELAXED, __HIP_MEMORY_SCOPE_AGENT);
          if (__ballot(v < (unsigned)(t + 1)) == 0ull) break;
        }
      }

      // stage h(t+1): 8 chunks per wave (oldest vm ops after the poll)
      const unsigned short* hsrcN = hbf + (size_t)((t + 1) & 1) * 131072 + (size_t)b0 * 1024;
      if (fast) {
#pragma unroll
        for (int j = 0; j < 8; ++j) {
          int blk = w * 8 + j;
          int m = blk >> 1, kh = blk & 1;
          gl_lds16_l2(hsrcN + m * 1024 + kh * 512 + ((lane ^ (m & 7)) * 8),
                      (unsigned short*)(At + m * 2048 + kh * 1024));
        }
      } else {
#pragma unroll
        for (int j = 0; j < 8; ++j) {
          int blk = w * 8 + j;
          int m = blk >> 1, kh = blk & 1;
          gl_lds16_coh(hsrcN + m * 1024 + kh * 512 + ((lane ^ (m & 7)) * 8),
                       (unsigned short*)(At + m * 2048 + kh * 1024));
        }
      }
      __builtin_amdgcn_sched_barrier(0);

      // fwx/g prefetch for t+1 (12 loads, youngest): hidden under barrier B +
      // next MFMA phase, consumed in the next epilogue via compiler waits
      if (matrix == 0) {
#pragma unroll
        for (int r = 0; r < 4; ++r) {
          int b = b0 + q * 4 + r;
          size_t base = (size_t)(t + 1) * 262144 + (size_t)b * 2048;
          fwru[r] = fwx[base + n_g];
          fwu[r]  = fwx[base + 1024 + n_g];
          gvv[r]  = g[b * 128 + (t + 1)];
        }
      }
      __builtin_amdgcn_sched_barrier(0);

      // ---- barrier B: staging drained (counted — fwx stays in flight) ----
      if (matrix == 0) asm volatile("s_waitcnt vmcnt(12)" ::: "memory");
      else             asm volatile("s_waitcnt vmcnt(0)"  ::: "memory");
      __builtin_amdgcn_sched_barrier(0);
      __builtin_amdgcn_s_barrier();
      __builtin_amdgcn_sched_barrier(0);
      asm volatile("" ::: "memory");
    }
  }
}

extern "C" void kernel_launch(void* const* d_in, const int* in_sizes, int n_in,
                              void* d_out, int out_size, void* d_ws, size_t ws_size,
                              hipStream_t stream) {
  const float* facts     = (const float*)d_in[0]; // [128][128][1024]
  const int*   num_facts = (const int*)d_in[1];   // [128]
  const float* g         = (const float*)d_in[2]; // [128][128][1]
  const float* mem_old   = (const float*)d_in[3]; // [128][1][1024]
  const float* Wr        = (const float*)d_in[4]; // [1024][1024]
  const float* Urw       = (const float*)d_in[5];
  const float* Urb       = (const float*)d_in[6];
  const float* W         = (const float*)d_in[7];
  const float* Uw        = (const float*)d_in[8];
  const float* Ub        = (const float*)d_in[9];

  // workspace layout (f16 elements unless noted)
  unsigned short* facts_h = (unsigned short*)d_ws;        // 16,777,216
  unsigned short* wstack  = facts_h + 16777216;           //  2,097,152 ([Wr|W])
  unsigned short* fwx     = wstack + 2097152;             // 33,554,432 ([t][b][2048])
  unsigned short* hbf     = fwx + 33554432;               //    262,144 (2 x [128][1024])
  unsigned int*   flg     = (unsigned int*)(hbf + 262144);// 8*32*2*16 u32 = 32KB
  unsigned int*   xcc     = flg + 8192;                   // 8*32*32 u32 = 32KB
  float* out = (float*)d_out;

  hipMemsetAsync(flg, 0, 2 * 8 * 32 * 32 * 4, stream);    // flg + xcc
  cvt_all<<<4096, 256, 0, stream>>>(
      (const float4*)facts,   (ushort4*)facts_h,
      (const float4*)Wr,      (ushort4*)wstack,
      (const float4*)W,       (ushort4*)(wstack + 1048576),
      (const float4*)mem_old, (ushort4*)hbf);
  gemm_fw<<<dim3(128, 16), 256, 0, stream>>>(facts_h, wstack, fwx);
  gru_recur<<<256, 256, 0, stream>>>(fwx, Urw, Urb, Uw, Ub, g, mem_old, num_facts, hbf, flg, xcc, out);
}